// Round 1
// 223.106 us; speedup vs baseline: 1.0896x; 1.0896x over previous
//
#include <hip/hip_runtime.h>

typedef unsigned short u16;
typedef unsigned int   u32;
typedef __attribute__((ext_vector_type(8))) short bf16x8;
typedef __attribute__((ext_vector_type(4))) float f32x4;

#define SEQ 2048
#define DIM 1024
#define NH  16
#define DH  64
#define NROW 4096

static __device__ __forceinline__ float bf2f(u16 v){
  u32 u = ((u32)v) << 16; float f; __builtin_memcpy(&f, &u, 4); return f;
}
static __device__ __forceinline__ u16 f2bf(float f){
  u32 u; __builtin_memcpy(&u, &f, 4);
  u32 r = (u + 0x7fffu + ((u >> 16) & 1u)) >> 16;
  return (u16)r;
}
// round-half-up pack of two fp32 -> two bf16 in one u32 (low = a, high = b)
static __device__ __forceinline__ u32 pack2bf(float a, float b){
  u32 ua, ub; __builtin_memcpy(&ua, &a, 4); __builtin_memcpy(&ub, &b, 4);
  return ((ua + 0x8000u) >> 16) | ((ub + 0x8000u) & 0xFFFF0000u);
}
// single-instruction RNE pack (lo = a, hi = b)
static __device__ __forceinline__ u32 cvt_pk_bf16(float a, float b){
  u32 r;
  asm("v_cvt_pk_bf16_f32 %0, %1, %2" : "=v"(r) : "v"(a), "v"(b));
  return r;
}

#define GLD_LDS(gp, lp) \
  __builtin_amdgcn_global_load_lds( \
      (const __attribute__((address_space(1))) void*)(gp), \
      (__attribute__((address_space(3))) void*)(lp), 16, 0, 0)

// ---------------- RMSNorm: x[4096][1024] fp32 -> h bf16 ----------------
__global__ __launch_bounds__(256) void k_rmsnorm(const float* __restrict__ x,
                                                 const float* __restrict__ sc,
                                                 u16* __restrict__ h){
  int row = blockIdx.x, t = threadIdx.x;
  float4 v = ((const float4*)(x + (size_t)row * DIM))[t];
  float ss = v.x*v.x + v.y*v.y + v.z*v.z + v.w*v.w;
  #pragma unroll
  for (int d = 32; d; d >>= 1) ss += __shfl_down(ss, d, 64);
  __shared__ float red[4];
  if ((t & 63) == 0) red[t >> 6] = ss;
  __syncthreads();
  float tot = red[0] + red[1] + red[2] + red[3];
  float rms = rsqrtf(tot * (1.0f / DIM) + 1e-6f);
  float4 s4 = ((const float4*)sc)[t];
  u16 ov[4];
  ov[0] = f2bf(v.x * rms * s4.x);
  ov[1] = f2bf(v.y * rms * s4.y);
  ov[2] = f2bf(v.z * rms * s4.z);
  ov[3] = f2bf(v.w * rms * s4.w);
  ((uint2*)(h + (size_t)row * DIM))[t] = *(uint2*)ov;
}

// ------- Weight transpose: fp32 K-major [1024][1024] -> bf16 N-major [n][k] -------
__global__ __launch_bounds__(256) void k_wtrans(const float* __restrict__ in0,
                                                const float* __restrict__ in1,
                                                const float* __restrict__ in2,
                                                u16* __restrict__ outT){
  __shared__ u16 tile[64][68];
  int t = threadIdx.x;
  int c0 = blockIdx.x * 64;   // n
  int r0 = blockIdx.y * 64;   // k
  int z = blockIdx.z;
  const float* in = (z == 0) ? in0 : ((z == 1) ? in1 : in2);
  u16* out = outT + (size_t)z * (1u << 20);
  #pragma unroll
  for (int i = 0; i < 4; i++){
    int idx = t + 256 * i;
    int r = idx >> 4, c4 = (idx & 15) * 4;
    float4 v = *(const float4*)&in[(size_t)(r0 + r) * 1024 + c0 + c4];
    u16 pk[4] = {f2bf(v.x), f2bf(v.y), f2bf(v.z), f2bf(v.w)};
    *(uint2*)&tile[r][c4] = *(uint2*)pk;
  }
  __syncthreads();
  #pragma unroll
  for (int i = 0; i < 2; i++){
    int c = t + 256 * i;
    int n = c >> 3, koff = (c & 7) * 8;
    alignas(16) u16 vals[8];
    #pragma unroll
    for (int j = 0; j < 8; j++) vals[j] = tile[koff + j][n];
    *(uint4*)&out[(size_t)(c0 + n) * 1024 + r0 + koff] = *(uint4*)vals;
  }
}

// ---------------- GEMM (m97 structure): C = A(bf16) x Bt^T (Bt bf16 N-major) ------
__global__ __launch_bounds__(256) void k_gemm(const u16* __restrict__ A,
                                              const u16* __restrict__ B0,
                                              const u16* __restrict__ B1,
                                              const u16* __restrict__ B2,
                                              void* __restrict__ C0,
                                              void* __restrict__ C1,
                                              void* __restrict__ C2,
                                              const float* __restrict__ bias,
                                              int qkv){
  __shared__ u16 Al[128][32];
  __shared__ u16 Bl[128][32];
  int t = threadIdx.x, lane = t & 63, w = t >> 6;
  int wm = w & 1, wn = w >> 1;
  int mrow = lane & 15, quad = lane >> 4;
  int m0 = blockIdx.x * 128, n0 = blockIdx.y * 128;
  int z = blockIdx.z;
  const u16* Bt = (z == 0) ? B0 : ((z == 1) ? B1 : B2);

  int r0s = (t * 16) >> 6, off0 = ((t * 16) & 63) >> 1;   // i=0
  int r1s = r0s + 64;                                     // i=1

  f32x4 acc[4][4];
  #pragma unroll
  for (int ms = 0; ms < 4; ms++)
    #pragma unroll
    for (int ns = 0; ns < 4; ns++) acc[ms][ns] = (f32x4){0.f, 0.f, 0.f, 0.f};

  for (int kt = 0; kt < 32; kt++){
    int K0 = kt * 32;
    __syncthreads();
    GLD_LDS(&A [(size_t)(m0 + r0s) * 1024 + K0 + off0], &Al[r0s][off0]);
    GLD_LDS(&A [(size_t)(m0 + r1s) * 1024 + K0 + off0], &Al[r1s][off0]);
    GLD_LDS(&Bt[(size_t)(n0 + r0s) * 1024 + K0 + off0], &Bl[r0s][off0]);
    GLD_LDS(&Bt[(size_t)(n0 + r1s) * 1024 + K0 + off0], &Bl[r1s][off0]);
    __syncthreads();
    bf16x8 af[4], bf[4];
    #pragma unroll
    for (int ms = 0; ms < 4; ms++)
      af[ms] = *(const bf16x8*)&Al[wm * 64 + ms * 16 + mrow][quad * 8];
    #pragma unroll
    for (int ns = 0; ns < 4; ns++)
      bf[ns] = *(const bf16x8*)&Bl[wn * 64 + ns * 16 + mrow][quad * 8];
    #pragma unroll
    for (int ms = 0; ms < 4; ms++)
      #pragma unroll
      for (int ns = 0; ns < 4; ns++)
        acc[ms][ns] = __builtin_amdgcn_mfma_f32_16x16x32_bf16(af[ms], bf[ns], acc[ms][ns], 0, 0, 0);
  }

  float qscale = (qkv && z == 0) ? 0.180336880111112f : 1.0f;
  bool  vmode  = (qkv && z == 2);
  void* C = (z == 0) ? C0 : ((z == 1) ? C1 : C2);

  #pragma unroll
  for (int ms = 0; ms < 4; ms++){
    #pragma unroll
    for (int ns = 0; ns < 4; ns++){
      int col = n0 + wn * 64 + ns * 16 + mrow;
      int rbase = m0 + wm * 64 + ms * 16 + quad * 4;
      if (vmode){
        int b = rbase >> 11, sl = rbase & 2047;
        int hh = col >> 6, e = col & 63;
        uint2 pk = { pack2bf(acc[ms][ns][0], acc[ms][ns][1]),
                     pack2bf(acc[ms][ns][2], acc[ms][ns][3]) };
        *(uint2*)&((u16*)C)[(size_t)((b * NH + hh) * DH + e) * SEQ + sl] = pk;
      } else if (qkv){
        #pragma unroll
        for (int r = 0; r < 4; r++)
          ((u16*)C)[(size_t)(rbase + r) * 1024 + col] = f2bf(acc[ms][ns][r] * qscale);
      } else {
        float bv = bias ? bias[col] : 0.f;
        #pragma unroll
        for (int r = 0; r < 4; r++)
          ((float*)C)[(size_t)(rbase + r) * 1024 + col] = acc[ms][ns][r] + bv;
      }
    }
  }
}

// ---------------- Flash attention, S^T formulation, 64 q-rows/block ----------------
// Restructured:
//  * K/V staged via global_load_lds (16B) into double-buffered, XOR-swizzled
//    linear LDS: content at physical (row, chunk p) = logical chunk p ^ f(row),
//    f(row) = (row&3) | (((row>>3)&1)<<2). Swizzle realized by pre-swizzling the
//    per-lane GLOBAL source address (LDS dest stays linear, lane*16).
//  * QK^T A-operand rows permuted per call g: row = pi_g(mrow),
//    pi_0(m) = (m>>2)*8 + (m&3), +4 / +32 / +36 for g=1..3. This makes each
//    lane's C output exactly the PV B-fragment (k = quad*8+j, n = mrow):
//    P never touches LDS, no cross-lane shuffle.
//  * Softmax denominator via ones x P MFMA (2 extra MFMA/kt) instead of
//    16 VALU adds + 2 shuffles.
//  * One barrier + vmcnt(0) per K-tile (issue next-tile GLDs, compute, drain).
__global__ __launch_bounds__(256) void k_attn(const u16* q,
                                              const u16* __restrict__ k,
                                              const u16* __restrict__ vt,
                                              u16* nv){
  __shared__ u16 Kl[2][64][64];
  __shared__ u16 Vl[2][64][64];
  int t = threadIdx.x, lane = t & 63, w = t >> 6;
  int mrow = lane & 15, quad = lane >> 4;
  int s0 = blockIdx.x * 64;
  int bh = blockIdx.y; int b = bh >> 4, hh = bh & 15;

  const u16* qrow = q + (size_t)((b * SEQ + s0 + w * 16 + mrow) * NH + hh) * DH;
  bf16x8 bq0 = *(const bf16x8*)(qrow + quad * 8);
  bf16x8 bq1 = *(const bf16x8*)(qrow + 32 + quad * 8);

  // staging coords: thread t writes LDS bytes (t+256i)*16 -> (row=(t>>3)+32i, p=t&7)
  // f(row) here: row&3 = (t>>3)&3 ; (row>>3)&1 = (t>>6)&1  (same for i=0,1)
  int rw  = t >> 3;
  int fst = (rw & 3) | (((t >> 6) & 1) << 2);
  int lc  = (t & 7) ^ fst;                        // logical chunk to fetch
  const u16* kp = k  + ((size_t)b * SEQ + rw) * (NH * DH) + hh * DH + lc * 8;
  const u16* vp = vt + ((size_t)bh * DH + rw) * SEQ + lc * 8;

  // read coords
  int row0 = ((mrow >> 2) << 3) | (mrow & 3);                       // pi_0(mrow)
  int cK = (quad ^ ((mrow & 3) | (((mrow >> 2) & 1) << 2))) << 4;   // byte of a0 chunk
  int cV = (quad ^ ((mrow & 3) | (((mrow >> 3) & 1) << 2))) << 4;

  f32x4 o[4];
  #pragma unroll
  for (int g = 0; g < 4; g++) o[g] = (f32x4){0.f, 0.f, 0.f, 0.f};
  f32x4 accl = (f32x4){0.f, 0.f, 0.f, 0.f};
  bf16x8 onesf;
  #pragma unroll
  for (int j = 0; j < 8; j++) onesf[j] = (short)0x3F80;             // bf16 1.0

  // prologue: stage tile 0 into buffer 0
  {
    u16* dK = &Kl[0][0][0]; u16* dV = &Vl[0][0][0];
    GLD_LDS(kp,                dK + (t << 3));
    GLD_LDS(kp + 32 * NH * DH, dK + ((t + 256) << 3));
    GLD_LDS(vp,                dV + (t << 3));
    GLD_LDS(vp + 32 * SEQ,     dV + ((t + 256) << 3));
    kp += 64 * NH * DH; vp += 64;
  }
  asm volatile("s_waitcnt vmcnt(0)" ::: "memory");
  __syncthreads();

  for (int kt = 0; kt < 32; kt++){
    int cur = kt & 1;
    if (kt < 31){                                  // issue next tile (async)
      u16* dK = &Kl[cur ^ 1][0][0]; u16* dV = &Vl[cur ^ 1][0][0];
      GLD_LDS(kp,                dK + (t << 3));
      GLD_LDS(kp + 32 * NH * DH, dK + ((t + 256) << 3));
      GLD_LDS(vp,                dV + (t << 3));
      GLD_LDS(vp + 32 * SEQ,     dV + ((t + 256) << 3));
      kp += 64 * NH * DH; vp += 64;
    }

    // QK^T with permuted rows: lane ends up holding S^T[kk = quad*8+j][q=mrow]
    const char* Kb = (const char*)Kl[cur];
    f32x4 sT[4];
    #pragma unroll
    for (int g = 0; g < 4; g++){
      int rg = row0 + ((g & 1) << 2) + ((g >> 1) << 5);   // +0,+4,+32,+36
      const char* rp = Kb + rg * 128;
      bf16x8 a0 = *(const bf16x8*)(rp + cK);
      bf16x8 a1 = *(const bf16x8*)(rp + (cK ^ 64));
      f32x4 zz = (f32x4){0.f, 0.f, 0.f, 0.f};
      zz = __builtin_amdgcn_mfma_f32_16x16x32_bf16(a0, bq0, zz, 0, 0, 0);
      zz = __builtin_amdgcn_mfma_f32_16x16x32_bf16(a1, bq1, zz, 0, 0, 0);
      sT[g] = zz;
    }

    // exp2 + pack in-register: pb0 = kk quad*8..+7 (g=0,1), pb1 = +32 (g=2,3)
    u32 wd[8];
    #pragma unroll
    for (int g = 0; g < 4; g++){
      float e0 = exp2f(sT[g][0]), e1 = exp2f(sT[g][1]);
      float e2 = exp2f(sT[g][2]), e3 = exp2f(sT[g][3]);
      wd[g * 2]     = cvt_pk_bf16(e0, e1);
      wd[g * 2 + 1] = cvt_pk_bf16(e2, e3);
    }
    union { u32 u[4]; bf16x8 v; } U0, U1;
    U0.u[0] = wd[0]; U0.u[1] = wd[1]; U0.u[2] = wd[2]; U0.u[3] = wd[3];
    U1.u[0] = wd[4]; U1.u[1] = wd[5]; U1.u[2] = wd[6]; U1.u[3] = wd[7];
    bf16x8 pb0 = U0.v, pb1 = U1.v;

    // denominator on the matrix pipe: every acc element = sum_kk P[kk][q=mrow]
    accl = __builtin_amdgcn_mfma_f32_16x16x32_bf16(onesf, pb0, accl, 0, 0, 0);
    accl = __builtin_amdgcn_mfma_f32_16x16x32_bf16(onesf, pb1, accl, 0, 0, 0);

    // O^T[e][q] += V^T[e][kk] . P[kk][q]
    const char* Vb = (const char*)Vl[cur];
    #pragma unroll
    for (int ge = 0; ge < 4; ge++){
      const char* rp = Vb + (ge * 16 + mrow) * 128;
      bf16x8 v0 = *(const bf16x8*)(rp + cV);
      bf16x8 v1 = *(const bf16x8*)(rp + (cV ^ 64));
      o[ge] = __builtin_amdgcn_mfma_f32_16x16x32_bf16(v0, pb0, o[ge], 0, 0, 0);
      o[ge] = __builtin_amdgcn_mfma_f32_16x16x32_bf16(v1, pb1, o[ge], 0, 0, 0);
    }

    asm volatile("s_waitcnt vmcnt(0)" ::: "memory");
    __syncthreads();
  }

  // epilogue: lane's q = mrow; e = ge*16 + quad*4 + r
  float rl = 1.0f / accl[0];
  u16* orow = nv + (size_t)((b * SEQ + s0 + w * 16 + mrow) * NH + hh) * DH;
  #pragma unroll
  for (int ge = 0; ge < 4; ge++){
    uint2 pk = { cvt_pk_bf16(o[ge][0] * rl, o[ge][1] * rl),
                 cvt_pk_bf16(o[ge][2] * rl, o[ge][3] * rl) };
    *(uint2*)&orow[ge * 16 + quad * 4] = pk;
  }
}

extern "C" void kernel_launch(void* const* d_in, const int* in_sizes, int n_in,
                              void* d_out, int out_size, void* d_ws, size_t ws_size,
                              hipStream_t stream){
  const float* x   = (const float*)d_in[0];
  const float* nsc = (const float*)d_in[1];
  const float* wq  = (const float*)d_in[2];
  const float* wk  = (const float*)d_in[3];
  const float* wv  = (const float*)d_in[4];
  const float* wo  = (const float*)d_in[5];
  const float* bo  = (const float*)d_in[6];
  char* ws = (char*)d_ws;
  const size_t MB = (size_t)1 << 20;

  u16* qb  = (u16*)(ws);
  u16* kb  = (u16*)(ws + 8  * MB);
  u16* vtb = (u16*)(ws + 16 * MB);
  u16* h   = (u16*)d_out;
  u16* wT  = (u16*)((char*)d_out + 8 * MB);
  u16* wqT = wT;
  u16* wkT = wT + (1u << 20);
  u16* wvT = wT + (2u << 20);
  u16* woT = kb;

  k_rmsnorm<<<NROW, 256, 0, stream>>>(x, nsc, h);
  k_wtrans<<<dim3(16, 16, 3), 256, 0, stream>>>(wq, wk, wv, wT);
  k_gemm<<<dim3(32, 8, 3), 256, 0, stream>>>(h, wqT, wkT, wvT, qb, kb, vtb, nullptr, 1);
  k_attn<<<dim3(32, 32, 1), 256, 0, stream>>>(qb, kb, vtb, qb);
  k_wtrans<<<dim3(16, 16, 1), 256, 0, stream>>>(wo, wo, wo, woT);
  k_gemm<<<dim3(32, 8, 1), 256, 0, stream>>>(qb, woT, woT, woT, d_out, d_out, d_out, bo, 0);
}

// Round 2
// 215.064 us; speedup vs baseline: 1.1304x; 1.0374x over previous
//
#include <hip/hip_runtime.h>

typedef unsigned short u16;
typedef unsigned int   u32;
typedef __attribute__((ext_vector_type(8))) short bf16x8;
typedef __attribute__((ext_vector_type(4))) float f32x4;

#define SEQ 2048
#define DIM 1024
#define NH  16
#define DH  64
#define NROW 4096

static __device__ __forceinline__ float bf2f(u16 v){
  u32 u = ((u32)v) << 16; float f; __builtin_memcpy(&f, &u, 4); return f;
}
static __device__ __forceinline__ u16 f2bf(float f){
  u32 u; __builtin_memcpy(&u, &f, 4);
  u32 r = (u + 0x7fffu + ((u >> 16) & 1u)) >> 16;
  return (u16)r;
}
// round-half-up pack of two fp32 -> two bf16 in one u32 (low = a, high = b)
static __device__ __forceinline__ u32 pack2bf(float a, float b){
  u32 ua, ub; __builtin_memcpy(&ua, &a, 4); __builtin_memcpy(&ub, &b, 4);
  return ((ua + 0x8000u) >> 16) | ((ub + 0x8000u) & 0xFFFF0000u);
}
// single-instruction RNE pack (lo = a, hi = b)
static __device__ __forceinline__ u32 cvt_pk_bf16(float a, float b){
  u32 r;
  asm("v_cvt_pk_bf16_f32 %0, %1, %2" : "=v"(r) : "v"(a), "v"(b));
  return r;
}

#define GLD_LDS(gp, lp) \
  __builtin_amdgcn_global_load_lds( \
      (const __attribute__((address_space(1))) void*)(gp), \
      (__attribute__((address_space(3))) void*)(lp), 16, 0, 0)

// ---------------- RMSNorm: x[4096][1024] fp32 -> h bf16 ----------------
__global__ __launch_bounds__(256) void k_rmsnorm(const float* __restrict__ x,
                                                 const float* __restrict__ sc,
                                                 u16* __restrict__ h){
  int row = blockIdx.x, t = threadIdx.x;
  float4 v = ((const float4*)(x + (size_t)row * DIM))[t];
  float ss = v.x*v.x + v.y*v.y + v.z*v.z + v.w*v.w;
  #pragma unroll
  for (int d = 32; d; d >>= 1) ss += __shfl_down(ss, d, 64);
  __shared__ float red[4];
  if ((t & 63) == 0) red[t >> 6] = ss;
  __syncthreads();
  float tot = red[0] + red[1] + red[2] + red[3];
  float rms = rsqrtf(tot * (1.0f / DIM) + 1e-6f);
  float4 s4 = ((const float4*)sc)[t];
  u16 ov[4];
  ov[0] = f2bf(v.x * rms * s4.x);
  ov[1] = f2bf(v.y * rms * s4.y);
  ov[2] = f2bf(v.z * rms * s4.z);
  ov[3] = f2bf(v.w * rms * s4.w);
  ((uint2*)(h + (size_t)row * DIM))[t] = *(uint2*)ov;
}

// ------- Weight transpose: fp32 K-major [1024][1024] -> bf16 N-major [n][k] -------
__global__ __launch_bounds__(256) void k_wtrans(const float* __restrict__ in0,
                                                const float* __restrict__ in1,
                                                const float* __restrict__ in2,
                                                u16* __restrict__ outT){
  __shared__ u16 tile[64][68];
  int t = threadIdx.x;
  int c0 = blockIdx.x * 64;   // n
  int r0 = blockIdx.y * 64;   // k
  int z = blockIdx.z;
  const float* in = (z == 0) ? in0 : ((z == 1) ? in1 : in2);
  u16* out = outT + (size_t)z * (1u << 20);
  #pragma unroll
  for (int i = 0; i < 4; i++){
    int idx = t + 256 * i;
    int r = idx >> 4, c4 = (idx & 15) * 4;
    float4 v = *(const float4*)&in[(size_t)(r0 + r) * 1024 + c0 + c4];
    u16 pk[4] = {f2bf(v.x), f2bf(v.y), f2bf(v.z), f2bf(v.w)};
    *(uint2*)&tile[r][c4] = *(uint2*)pk;
  }
  __syncthreads();
  #pragma unroll
  for (int i = 0; i < 2; i++){
    int c = t + 256 * i;
    int n = c >> 3, koff = (c & 7) * 8;
    alignas(16) u16 vals[8];
    #pragma unroll
    for (int j = 0; j < 8; j++) vals[j] = tile[koff + j][n];
    *(uint4*)&out[(size_t)(c0 + n) * 1024 + r0 + koff] = *(uint4*)vals;
  }
}

// ---------------- GEMM: C = A(bf16) x Bt^T, 2-phase double-buffered ----------------
// Block 128m x 128n, BK=32, 4 waves 2x2 (64x64 each, 4x4 acc).
// T3-minimum 2-phase: issue next K-tile's global_load_lds BEFORE computing the
// current tile; single barrier per kt (its implied vmcnt(0)/lgkmcnt(0) drain
// covers both the prefetch and this tile's ds_reads). Hides global load latency
// under the 16-MFMA compute phase (previous 1-phase exposed it serially).
__global__ __launch_bounds__(256) void k_gemm(const u16* __restrict__ A,
                                              const u16* __restrict__ B0,
                                              const u16* __restrict__ B1,
                                              const u16* __restrict__ B2,
                                              void* __restrict__ C0,
                                              void* __restrict__ C1,
                                              void* __restrict__ C2,
                                              const float* __restrict__ bias,
                                              int qkv){
  __shared__ u16 Al[2][128][32];
  __shared__ u16 Bl[2][128][32];
  int t = threadIdx.x, lane = t & 63, w = t >> 6;
  int wm = w & 1, wn = w >> 1;
  int mrow = lane & 15, quad = lane >> 4;
  int m0 = blockIdx.x * 128, n0 = blockIdx.y * 128;
  int z = blockIdx.z;
  const u16* Bt = (z == 0) ? B0 : ((z == 1) ? B1 : B2);

  int r0s = (t * 16) >> 6, off0 = ((t * 16) & 63) >> 1;   // i=0
  int r1s = r0s + 64;                                     // i=1

  const u16* Ap0 = &A [(size_t)(m0 + r0s) * 1024 + off0];
  const u16* Ap1 = &A [(size_t)(m0 + r1s) * 1024 + off0];
  const u16* Bp0 = &Bt[(size_t)(n0 + r0s) * 1024 + off0];
  const u16* Bp1 = &Bt[(size_t)(n0 + r1s) * 1024 + off0];

  f32x4 acc[4][4];
  #pragma unroll
  for (int ms = 0; ms < 4; ms++)
    #pragma unroll
    for (int ns = 0; ns < 4; ns++) acc[ms][ns] = (f32x4){0.f, 0.f, 0.f, 0.f};

  // prologue: stage tile 0 into buffer 0
  GLD_LDS(Ap0, &Al[0][r0s][off0]);
  GLD_LDS(Ap1, &Al[0][r1s][off0]);
  GLD_LDS(Bp0, &Bl[0][r0s][off0]);
  GLD_LDS(Bp1, &Bl[0][r1s][off0]);
  __syncthreads();

  for (int kt = 0; kt < 32; kt++){
    int cur = kt & 1;
    if (kt < 31){
      int K1 = (kt + 1) * 32;
      GLD_LDS(Ap0 + K1, &Al[cur ^ 1][r0s][off0]);
      GLD_LDS(Ap1 + K1, &Al[cur ^ 1][r1s][off0]);
      GLD_LDS(Bp0 + K1, &Bl[cur ^ 1][r0s][off0]);
      GLD_LDS(Bp1 + K1, &Bl[cur ^ 1][r1s][off0]);
    }
    bf16x8 af[4], bfr[4];
    #pragma unroll
    for (int ms = 0; ms < 4; ms++)
      af[ms] = *(const bf16x8*)&Al[cur][wm * 64 + ms * 16 + mrow][quad * 8];
    #pragma unroll
    for (int ns = 0; ns < 4; ns++)
      bfr[ns] = *(const bf16x8*)&Bl[cur][wn * 64 + ns * 16 + mrow][quad * 8];
    #pragma unroll
    for (int ms = 0; ms < 4; ms++)
      #pragma unroll
      for (int ns = 0; ns < 4; ns++)
        acc[ms][ns] = __builtin_amdgcn_mfma_f32_16x16x32_bf16(af[ms], bfr[ns], acc[ms][ns], 0, 0, 0);
    __syncthreads();
  }

  float qscale = (qkv && z == 0) ? 0.180336880111112f : 1.0f;
  bool  vmode  = (qkv && z == 2);
  void* C = (z == 0) ? C0 : ((z == 1) ? C1 : C2);

  #pragma unroll
  for (int ms = 0; ms < 4; ms++){
    #pragma unroll
    for (int ns = 0; ns < 4; ns++){
      int col = n0 + wn * 64 + ns * 16 + mrow;
      int rbase = m0 + wm * 64 + ms * 16 + quad * 4;
      if (vmode){
        int b = rbase >> 11, sl = rbase & 2047;
        int hh = col >> 6, e = col & 63;
        uint2 pk = { pack2bf(acc[ms][ns][0], acc[ms][ns][1]),
                     pack2bf(acc[ms][ns][2], acc[ms][ns][3]) };
        *(uint2*)&((u16*)C)[(size_t)((b * NH + hh) * DH + e) * SEQ + sl] = pk;
      } else if (qkv){
        #pragma unroll
        for (int r = 0; r < 4; r++)
          ((u16*)C)[(size_t)(rbase + r) * 1024 + col] = f2bf(acc[ms][ns][r] * qscale);
      } else {
        float bv = bias ? bias[col] : 0.f;
        #pragma unroll
        for (int r = 0; r < 4; r++)
          ((float*)C)[(size_t)(rbase + r) * 1024 + col] = acc[ms][ns][r] + bv;
      }
    }
  }
}

// ---------------- Flash attention, S^T formulation, 128 q-rows/block ----------------
// 8 waves x 16 q-rows over a shared 64-row K/V tile: halves per-q-row staging
// traffic and barrier count vs the 4-wave version, raises waves/CU 10 -> 16.
// Staging: exactly one 16B global_load_lds per thread for K and one for V,
// double-buffered XOR-swizzled linear LDS (dest = base + t*16, source chunk
// pre-swizzled by f(row) = (row&3) | (((row>>3)&1)<<2)).
// QK^T A-rows permuted so each lane's C output IS the PV B-fragment; P stays
// in registers. Denominator via ones x P MFMA.
__global__ __launch_bounds__(512) void k_attn(const u16* q,
                                              const u16* __restrict__ k,
                                              const u16* __restrict__ vt,
                                              u16* nv){
  __shared__ u16 Kl[2][64][64];
  __shared__ u16 Vl[2][64][64];
  int t = threadIdx.x, lane = t & 63, w = t >> 6;    // w in 0..7
  int mrow = lane & 15, quad = lane >> 4;
  int s0 = blockIdx.x * 128;
  int bh = blockIdx.y; int b = bh >> 4, hh = bh & 15;

  const u16* qrow = q + (size_t)((b * SEQ + s0 + w * 16 + mrow) * NH + hh) * DH;
  bf16x8 bq0 = *(const bf16x8*)(qrow + quad * 8);
  bf16x8 bq1 = *(const bf16x8*)(qrow + 32 + quad * 8);

  // staging coords: thread t (0..511) writes LDS bytes t*16 -> (row=t>>3, p=t&7)
  // f(row): row&3 = (t>>3)&3 ; (row>>3)&1 = (t>>6)&1
  int rw  = t >> 3;                                  // 0..63
  int fst = (rw & 3) | (((t >> 6) & 1) << 2);
  int lc  = (t & 7) ^ fst;                           // logical chunk to fetch
  const u16* kp = k  + ((size_t)b * SEQ + rw) * (NH * DH) + hh * DH + lc * 8;
  const u16* vp = vt + ((size_t)bh * DH + rw) * SEQ + lc * 8;

  // read coords
  int row0 = ((mrow >> 2) << 3) | (mrow & 3);                       // pi_0(mrow)
  int cK = (quad ^ ((mrow & 3) | (((mrow >> 2) & 1) << 2))) << 4;   // byte of a0 chunk
  int cV = (quad ^ ((mrow & 3) | (((mrow >> 3) & 1) << 2))) << 4;

  f32x4 o[4];
  #pragma unroll
  for (int g = 0; g < 4; g++) o[g] = (f32x4){0.f, 0.f, 0.f, 0.f};
  f32x4 accl = (f32x4){0.f, 0.f, 0.f, 0.f};
  bf16x8 onesf;
  #pragma unroll
  for (int j = 0; j < 8; j++) onesf[j] = (short)0x3F80;             // bf16 1.0

  // prologue: stage tile 0 into buffer 0
  GLD_LDS(kp, &Kl[0][0][0] + (t << 3));
  GLD_LDS(vp, &Vl[0][0][0] + (t << 3));
  kp += 64 * NH * DH; vp += 64;
  __syncthreads();

  for (int kt = 0; kt < 32; kt++){
    int cur = kt & 1;
    if (kt < 31){                                  // issue next tile (async)
      GLD_LDS(kp, &Kl[cur ^ 1][0][0] + (t << 3));
      GLD_LDS(vp, &Vl[cur ^ 1][0][0] + (t << 3));
      kp += 64 * NH * DH; vp += 64;
    }

    // QK^T with permuted rows: lane holds S^T[kk = quad*8+j][q=mrow]
    const char* Kb = (const char*)Kl[cur];
    f32x4 sT[4];
    #pragma unroll
    for (int g = 0; g < 4; g++){
      int rg = row0 + ((g & 1) << 2) + ((g >> 1) << 5);   // +0,+4,+32,+36
      const char* rp = Kb + rg * 128;
      bf16x8 a0 = *(const bf16x8*)(rp + cK);
      bf16x8 a1 = *(const bf16x8*)(rp + (cK ^ 64));
      f32x4 zz = (f32x4){0.f, 0.f, 0.f, 0.f};
      zz = __builtin_amdgcn_mfma_f32_16x16x32_bf16(a0, bq0, zz, 0, 0, 0);
      zz = __builtin_amdgcn_mfma_f32_16x16x32_bf16(a1, bq1, zz, 0, 0, 0);
      sT[g] = zz;
    }

    // exp2 + pack in-register: pb0 = kk quad*8..+7 (g=0,1), pb1 = +32 (g=2,3)
    u32 wd[8];
    #pragma unroll
    for (int g = 0; g < 4; g++){
      float e0 = exp2f(sT[g][0]), e1 = exp2f(sT[g][1]);
      float e2 = exp2f(sT[g][2]), e3 = exp2f(sT[g][3]);
      wd[g * 2]     = cvt_pk_bf16(e0, e1);
      wd[g * 2 + 1] = cvt_pk_bf16(e2, e3);
    }
    union { u32 u[4]; bf16x8 v; } U0, U1;
    U0.u[0] = wd[0]; U0.u[1] = wd[1]; U0.u[2] = wd[2]; U0.u[3] = wd[3];
    U1.u[0] = wd[4]; U1.u[1] = wd[5]; U1.u[2] = wd[6]; U1.u[3] = wd[7];
    bf16x8 pb0 = U0.v, pb1 = U1.v;

    // denominator on the matrix pipe
    accl = __builtin_amdgcn_mfma_f32_16x16x32_bf16(onesf, pb0, accl, 0, 0, 0);
    accl = __builtin_amdgcn_mfma_f32_16x16x32_bf16(onesf, pb1, accl, 0, 0, 0);

    // O^T[e][q] += V^T[e][kk] . P[kk][q]
    const char* Vb = (const char*)Vl[cur];
    #pragma unroll
    for (int ge = 0; ge < 4; ge++){
      const char* rp = Vb + (ge * 16 + mrow) * 128;
      bf16x8 v0 = *(const bf16x8*)(rp + cV);
      bf16x8 v1 = *(const bf16x8*)(rp + (cV ^ 64));
      o[ge] = __builtin_amdgcn_mfma_f32_16x16x32_bf16(v0, pb0, o[ge], 0, 0, 0);
      o[ge] = __builtin_amdgcn_mfma_f32_16x16x32_bf16(v1, pb1, o[ge], 0, 0, 0);
    }

    __syncthreads();   // implied vmcnt(0)/lgkmcnt(0) drains prefetch + reads
  }

  // epilogue: lane's q = mrow; e = ge*16 + quad*4 + r
  float rl = 1.0f / accl[0];
  u16* orow = nv + (size_t)((b * SEQ + s0 + w * 16 + mrow) * NH + hh) * DH;
  #pragma unroll
  for (int ge = 0; ge < 4; ge++){
    uint2 pk = { cvt_pk_bf16(o[ge][0] * rl, o[ge][1] * rl),
                 cvt_pk_bf16(o[ge][2] * rl, o[ge][3] * rl) };
    *(uint2*)&orow[ge * 16 + quad * 4] = pk;
  }
}

extern "C" void kernel_launch(void* const* d_in, const int* in_sizes, int n_in,
                              void* d_out, int out_size, void* d_ws, size_t ws_size,
                              hipStream_t stream){
  const float* x   = (const float*)d_in[0];
  const float* nsc = (const float*)d_in[1];
  const float* wq  = (const float*)d_in[2];
  const float* wk  = (const float*)d_in[3];
  const float* wv  = (const float*)d_in[4];
  const float* wo  = (const float*)d_in[5];
  const float* bo  = (const float*)d_in[6];
  char* ws = (char*)d_ws;
  const size_t MB = (size_t)1 << 20;

  u16* qb  = (u16*)(ws);
  u16* kb  = (u16*)(ws + 8  * MB);
  u16* vtb = (u16*)(ws + 16 * MB);
  u16* h   = (u16*)d_out;
  u16* wT  = (u16*)((char*)d_out + 8 * MB);
  u16* wqT = wT;
  u16* wkT = wT + (1u << 20);
  u16* wvT = wT + (2u << 20);
  u16* woT = kb;

  k_rmsnorm<<<NROW, 256, 0, stream>>>(x, nsc, h);
  k_wtrans<<<dim3(16, 16, 3), 256, 0, stream>>>(wq, wk, wv, wT);
  k_gemm<<<dim3(32, 8, 3), 256, 0, stream>>>(h, wqT, wkT, wvT, qb, kb, vtb, nullptr, 1);
  k_attn<<<dim3(16, 32, 1), 512, 0, stream>>>(qb, kb, vtb, qb);
  k_wtrans<<<dim3(16, 16, 1), 256, 0, stream>>>(wo, wo, wo, woT);
  k_gemm<<<dim3(32, 8, 1), 256, 0, stream>>>(qb, woT, woT, woT, d_out, d_out, d_out, bo, 0);
}

// Round 3
// 210.646 us; speedup vs baseline: 1.1541x; 1.0210x over previous
//
#include <hip/hip_runtime.h>

typedef unsigned short u16;
typedef unsigned int   u32;
typedef __attribute__((ext_vector_type(8))) short bf16x8;
typedef __attribute__((ext_vector_type(4))) float f32x4;

#define SEQ 2048
#define DIM 1024
#define NH  16
#define DH  64
#define NROW 4096

static __device__ __forceinline__ u16 f2bf(float f){
  u32 u; __builtin_memcpy(&u, &f, 4);
  u32 r = (u + 0x7fffu + ((u >> 16) & 1u)) >> 16;
  return (u16)r;
}
// round-half-up pack of two fp32 -> two bf16 in one u32 (low = a, high = b)
static __device__ __forceinline__ u32 pack2bf(float a, float b){
  u32 ua, ub; __builtin_memcpy(&ua, &a, 4); __builtin_memcpy(&ub, &b, 4);
  return ((ua + 0x8000u) >> 16) | ((ub + 0x8000u) & 0xFFFF0000u);
}
// single-instruction RNE pack (lo = a, hi = b)
static __device__ __forceinline__ u32 cvt_pk_bf16(float a, float b){
  u32 r;
  asm("v_cvt_pk_bf16_f32 %0, %1, %2" : "=v"(r) : "v"(a), "v"(b));
  return r;
}

#define GLD_LDS(gp, lp) \
  __builtin_amdgcn_global_load_lds( \
      (const __attribute__((address_space(1))) void*)(gp), \
      (__attribute__((address_space(3))) void*)(lp), 16, 0, 0)

// counted waitcnt with compiler memory fence (blocks ds_read/GLD motion across)
#define WAIT_VM(N) asm volatile("s_waitcnt vmcnt(" #N ")" ::: "memory")
#define CFENCE()   asm volatile("" ::: "memory")

// ---------------- RMSNorm: x[4096][1024] fp32 -> h bf16 ----------------
__global__ __launch_bounds__(256) void k_rmsnorm(const float* __restrict__ x,
                                                 const float* __restrict__ sc,
                                                 u16* __restrict__ h){
  int row = blockIdx.x, t = threadIdx.x;
  float4 v = ((const float4*)(x + (size_t)row * DIM))[t];
  float ss = v.x*v.x + v.y*v.y + v.z*v.z + v.w*v.w;
  #pragma unroll
  for (int d = 32; d; d >>= 1) ss += __shfl_down(ss, d, 64);
  __shared__ float red[4];
  if ((t & 63) == 0) red[t >> 6] = ss;
  __syncthreads();
  float tot = red[0] + red[1] + red[2] + red[3];
  float rms = rsqrtf(tot * (1.0f / DIM) + 1e-6f);
  float4 s4 = ((const float4*)sc)[t];
  u16 ov[4];
  ov[0] = f2bf(v.x * rms * s4.x);
  ov[1] = f2bf(v.y * rms * s4.y);
  ov[2] = f2bf(v.z * rms * s4.z);
  ov[3] = f2bf(v.w * rms * s4.w);
  ((uint2*)(h + (size_t)row * DIM))[t] = *(uint2*)ov;
}

// ------- Weight transpose: fp32 K-major [1024][1024] -> bf16 N-major [n][k] -------
__global__ __launch_bounds__(256) void k_wtrans(const float* __restrict__ in0,
                                                const float* __restrict__ in1,
                                                const float* __restrict__ in2,
                                                u16* __restrict__ outT){
  __shared__ u16 tile[64][68];
  int t = threadIdx.x;
  int c0 = blockIdx.x * 64;   // n
  int r0 = blockIdx.y * 64;   // k
  int z = blockIdx.z;
  const float* in = (z == 0) ? in0 : ((z == 1) ? in1 : in2);
  u16* out = outT + (size_t)z * (1u << 20);
  #pragma unroll
  for (int i = 0; i < 4; i++){
    int idx = t + 256 * i;
    int r = idx >> 4, c4 = (idx & 15) * 4;
    float4 v = *(const float4*)&in[(size_t)(r0 + r) * 1024 + c0 + c4];
    u16 pk[4] = {f2bf(v.x), f2bf(v.y), f2bf(v.z), f2bf(v.w)};
    *(uint2*)&tile[r][c4] = *(uint2*)pk;
  }
  __syncthreads();
  #pragma unroll
  for (int i = 0; i < 2; i++){
    int c = t + 256 * i;
    int n = c >> 3, koff = (c & 7) * 8;
    alignas(16) u16 vals[8];
    #pragma unroll
    for (int j = 0; j < 8; j++) vals[j] = tile[koff + j][n];
    *(uint4*)&out[(size_t)(c0 + n) * 1024 + r0 + koff] = *(uint4*)vals;
  }
}

// ---------------- GEMM: C = A(bf16) x Bt^T, triple-buffered counted-vmcnt ---------
// Block 128m x 128n, BK=32, 4 waves 2x2. Per kt: vmcnt(4) (tile kt landed; tile
// kt+1 in flight) -> raw s_barrier -> issue tile kt+2 -> compute tile kt. The
// barrier never waits on freshly-issued loads (T4: counted vmcnt, never 0 in
// the main loop); each staging load gets ~2 compute phases of cover.
// XCD swizzle: 1D grid, 8-way chunked so consecutive wgs share an L2.
__global__ __launch_bounds__(256) void k_gemm(const u16* __restrict__ A,
                                              const u16* __restrict__ B0,
                                              const u16* __restrict__ B1,
                                              const u16* __restrict__ B2,
                                              void* __restrict__ C0,
                                              void* __restrict__ C1,
                                              void* __restrict__ C2,
                                              const float* __restrict__ bias,
                                              int qkv){
  __shared__ u16 Al[3][128][32];
  __shared__ u16 Bl[3][128][32];
  int t = threadIdx.x, lane = t & 63, w = t >> 6;
  int wm = w & 1, wn = w >> 1;
  int mrow = lane & 15, quad = lane >> 4;

  int nwgs = qkv ? 768 : 256;
  int cpx = nwgs >> 3;
  int id = blockIdx.x;
  int wg = (id & 7) * cpx + (id >> 3);
  int z = wg >> 8;
  int rem = wg & 255;
  int m0 = (rem >> 3) << 7;   // m-minor within XCD chunk: A tiles + B panels co-resident in L2
  int n0 = (rem & 7) << 7;
  const u16* Bt = (z == 0) ? B0 : ((z == 1) ? B1 : B2);

  int r0s = (t * 16) >> 6, off0 = ((t * 16) & 63) >> 1;   // i=0
  int r1s = r0s + 64;                                     // i=1

  const u16* Ap0 = &A [(size_t)(m0 + r0s) * 1024 + off0];
  const u16* Ap1 = &A [(size_t)(m0 + r1s) * 1024 + off0];
  const u16* Bp0 = &Bt[(size_t)(n0 + r0s) * 1024 + off0];
  const u16* Bp1 = &Bt[(size_t)(n0 + r1s) * 1024 + off0];

  f32x4 acc[4][4];
  #pragma unroll
  for (int ms = 0; ms < 4; ms++)
    #pragma unroll
    for (int ns = 0; ns < 4; ns++) acc[ms][ns] = (f32x4){0.f, 0.f, 0.f, 0.f};

  // prologue: stage tiles 0 and 1
  GLD_LDS(Ap0,      &Al[0][r0s][off0]);
  GLD_LDS(Ap1,      &Al[0][r1s][off0]);
  GLD_LDS(Bp0,      &Bl[0][r0s][off0]);
  GLD_LDS(Bp1,      &Bl[0][r1s][off0]);
  GLD_LDS(Ap0 + 32, &Al[1][r0s][off0]);
  GLD_LDS(Ap1 + 32, &Al[1][r1s][off0]);
  GLD_LDS(Bp0 + 32, &Bl[1][r0s][off0]);
  GLD_LDS(Bp1 + 32, &Bl[1][r1s][off0]);

  int cur = 0, pf = 2;
  for (int kt = 0; kt < 32; kt++){
    if (kt < 31) WAIT_VM(4); else WAIT_VM(0);
    __builtin_amdgcn_s_barrier();
    CFENCE();
    if (kt < 30){
      int K2 = (kt + 2) * 32;
      GLD_LDS(Ap0 + K2, &Al[pf][r0s][off0]);
      GLD_LDS(Ap1 + K2, &Al[pf][r1s][off0]);
      GLD_LDS(Bp0 + K2, &Bl[pf][r0s][off0]);
      GLD_LDS(Bp1 + K2, &Bl[pf][r1s][off0]);
    }
    bf16x8 af[4], bfr[4];
    #pragma unroll
    for (int ms = 0; ms < 4; ms++)
      af[ms] = *(const bf16x8*)&Al[cur][wm * 64 + ms * 16 + mrow][quad * 8];
    #pragma unroll
    for (int ns = 0; ns < 4; ns++)
      bfr[ns] = *(const bf16x8*)&Bl[cur][wn * 64 + ns * 16 + mrow][quad * 8];
    #pragma unroll
    for (int ms = 0; ms < 4; ms++)
      #pragma unroll
      for (int ns = 0; ns < 4; ns++)
        acc[ms][ns] = __builtin_amdgcn_mfma_f32_16x16x32_bf16(af[ms], bfr[ns], acc[ms][ns], 0, 0, 0);
    cur = (cur == 2) ? 0 : cur + 1;
    pf  = (pf  == 2) ? 0 : pf  + 1;
  }

  float qscale = (qkv && z == 0) ? 0.180336880111112f : 1.0f;
  bool  vmode  = (qkv && z == 2);
  void* C = (z == 0) ? C0 : ((z == 1) ? C1 : C2);

  #pragma unroll
  for (int ms = 0; ms < 4; ms++){
    #pragma unroll
    for (int ns = 0; ns < 4; ns++){
      int col = n0 + wn * 64 + ns * 16 + mrow;
      int rbase = m0 + wm * 64 + ms * 16 + quad * 4;
      if (vmode){
        int b = rbase >> 11, sl = rbase & 2047;
        int hh = col >> 6, e = col & 63;
        uint2 pk = { pack2bf(acc[ms][ns][0], acc[ms][ns][1]),
                     pack2bf(acc[ms][ns][2], acc[ms][ns][3]) };
        *(uint2*)&((u16*)C)[(size_t)((b * NH + hh) * DH + e) * SEQ + sl] = pk;
      } else if (qkv){
        #pragma unroll
        for (int r = 0; r < 4; r++)
          ((u16*)C)[(size_t)(rbase + r) * 1024 + col] = f2bf(acc[ms][ns][r] * qscale);
      } else {
        float bv = bias ? bias[col] : 0.f;
        #pragma unroll
        for (int r = 0; r < 4; r++)
          ((float*)C)[(size_t)(rbase + r) * 1024 + col] = acc[ms][ns][r] + bv;
      }
    }
  }
}

// ---------------- Flash attention, S^T formulation, 128 q-rows/block ----------------
// 8 waves x 16 q-rows over a shared 64-row K/V tile. Triple-buffered staging with
// counted vmcnt(2) + raw s_barrier (never drains fresh loads); issue-after-barrier
// makes the WAR on buf[(kt+2)%3] safe. XOR-swizzled linear LDS via pre-swizzled
// global source, f(row) = (row&3) | (((row>>3)&1)<<2). QK^T A-rows permuted so each
// lane's C output IS the PV B-fragment; P stays in registers. Denominator via
// ones x P MFMA. setprio(1) around MFMA clusters (T5). XCD swizzle: all 16
// s0-blocks of a head land on one XCD (4 heads x 512 KB K/V = 2 MB, L2-resident).
__global__ __launch_bounds__(512) void k_attn(const u16* q,
                                              const u16* __restrict__ k,
                                              const u16* __restrict__ vt,
                                              u16* nv){
  __shared__ u16 Kl[3][64][64];
  __shared__ u16 Vl[3][64][64];
  int t = threadIdx.x, lane = t & 63, w = t >> 6;    // w in 0..7
  int mrow = lane & 15, quad = lane >> 4;
  int id = blockIdx.x;
  int wg = (id & 7) * 64 + (id >> 3);                // 512 wgs, 64/XCD chunk
  int s0 = (wg & 15) * 128;
  int bh = wg >> 4; int b = bh >> 4, hh = bh & 15;

  const u16* qrow = q + (size_t)((b * SEQ + s0 + w * 16 + mrow) * NH + hh) * DH;
  bf16x8 bq0 = *(const bf16x8*)(qrow + quad * 8);
  bf16x8 bq1 = *(const bf16x8*)(qrow + 32 + quad * 8);

  // staging coords: thread t (0..511) writes LDS bytes t*16 -> (row=t>>3, p=t&7)
  int rw  = t >> 3;                                  // 0..63
  int fst = (rw & 3) | (((t >> 6) & 1) << 2);
  int lc  = (t & 7) ^ fst;                           // logical chunk to fetch
  const u16* kp = k  + ((size_t)b * SEQ + rw) * (NH * DH) + hh * DH + lc * 8;
  const u16* vp = vt + ((size_t)bh * DH + rw) * SEQ + lc * 8;

  // read coords
  int row0 = ((mrow >> 2) << 3) | (mrow & 3);                       // pi_0(mrow)
  int cK = (quad ^ ((mrow & 3) | (((mrow >> 2) & 1) << 2))) << 4;   // byte of a0 chunk
  int cV = (quad ^ ((mrow & 3) | (((mrow >> 3) & 1) << 2))) << 4;

  f32x4 o[4];
  #pragma unroll
  for (int g = 0; g < 4; g++) o[g] = (f32x4){0.f, 0.f, 0.f, 0.f};
  f32x4 accl = (f32x4){0.f, 0.f, 0.f, 0.f};
  bf16x8 onesf;
  #pragma unroll
  for (int j = 0; j < 8; j++) onesf[j] = (short)0x3F80;             // bf16 1.0

  // prologue: stage tiles 0 and 1
  GLD_LDS(kp, (u16*)Kl[0] + (t << 3));
  GLD_LDS(vp, (u16*)Vl[0] + (t << 3));
  kp += 64 * NH * DH; vp += 64;
  GLD_LDS(kp, (u16*)Kl[1] + (t << 3));
  GLD_LDS(vp, (u16*)Vl[1] + (t << 3));
  kp += 64 * NH * DH; vp += 64;

  int cur = 0, pf = 2;
  for (int kt = 0; kt < 32; kt++){
    if (kt < 31) WAIT_VM(2); else WAIT_VM(0);
    __builtin_amdgcn_s_barrier();
    CFENCE();
    if (kt < 30){                                    // issue tile kt+2 (async)
      GLD_LDS(kp, (u16*)Kl[pf] + (t << 3));
      GLD_LDS(vp, (u16*)Vl[pf] + (t << 3));
      kp += 64 * NH * DH; vp += 64;
    }

    // QK^T with permuted rows: lane holds S^T[kk = quad*8+j][q=mrow]
    const char* Kb = (const char*)Kl[cur];
    f32x4 sT[4];
    __builtin_amdgcn_s_setprio(1);
    #pragma unroll
    for (int g = 0; g < 4; g++){
      int rg = row0 + ((g & 1) << 2) + ((g >> 1) << 5);   // +0,+4,+32,+36
      const char* rp = Kb + rg * 128;
      bf16x8 a0 = *(const bf16x8*)(rp + cK);
      bf16x8 a1 = *(const bf16x8*)(rp + (cK ^ 64));
      f32x4 zz = (f32x4){0.f, 0.f, 0.f, 0.f};
      zz = __builtin_amdgcn_mfma_f32_16x16x32_bf16(a0, bq0, zz, 0, 0, 0);
      zz = __builtin_amdgcn_mfma_f32_16x16x32_bf16(a1, bq1, zz, 0, 0, 0);
      sT[g] = zz;
    }
    __builtin_amdgcn_s_setprio(0);

    // exp2 + pack in-register: pb0 = kk quad*8..+7 (g=0,1), pb1 = +32 (g=2,3)
    u32 wd[8];
    #pragma unroll
    for (int g = 0; g < 4; g++){
      float e0 = exp2f(sT[g][0]), e1 = exp2f(sT[g][1]);
      float e2 = exp2f(sT[g][2]), e3 = exp2f(sT[g][3]);
      wd[g * 2]     = cvt_pk_bf16(e0, e1);
      wd[g * 2 + 1] = cvt_pk_bf16(e2, e3);
    }
    union { u32 u[4]; bf16x8 v; } U0, U1;
    U0.u[0] = wd[0]; U0.u[1] = wd[1]; U0.u[2] = wd[2]; U0.u[3] = wd[3];
    U1.u[0] = wd[4]; U1.u[1] = wd[5]; U1.u[2] = wd[6]; U1.u[3] = wd[7];
    bf16x8 pb0 = U0.v, pb1 = U1.v;

    __builtin_amdgcn_s_setprio(1);
    // denominator on the matrix pipe
    accl = __builtin_amdgcn_mfma_f32_16x16x32_bf16(onesf, pb0, accl, 0, 0, 0);
    accl = __builtin_amdgcn_mfma_f32_16x16x32_bf16(onesf, pb1, accl, 0, 0, 0);

    // O^T[e][q] += V^T[e][kk] . P[kk][q]
    const char* Vb = (const char*)Vl[cur];
    #pragma unroll
    for (int ge = 0; ge < 4; ge++){
      const char* rp = Vb + (ge * 16 + mrow) * 128;
      bf16x8 v0 = *(const bf16x8*)(rp + cV);
      bf16x8 v1 = *(const bf16x8*)(rp + (cV ^ 64));
      o[ge] = __builtin_amdgcn_mfma_f32_16x16x32_bf16(v0, pb0, o[ge], 0, 0, 0);
      o[ge] = __builtin_amdgcn_mfma_f32_16x16x32_bf16(v1, pb1, o[ge], 0, 0, 0);
    }
    __builtin_amdgcn_s_setprio(0);

    cur = (cur == 2) ? 0 : cur + 1;
    pf  = (pf  == 2) ? 0 : pf  + 1;
  }

  // epilogue: lane's q = mrow; e = ge*16 + quad*4 + r
  float rl = 1.0f / accl[0];
  u16* orow = nv + (size_t)((b * SEQ + s0 + w * 16 + mrow) * NH + hh) * DH;
  #pragma unroll
  for (int ge = 0; ge < 4; ge++){
    uint2 pk = { cvt_pk_bf16(o[ge][0] * rl, o[ge][1] * rl),
                 cvt_pk_bf16(o[ge][2] * rl, o[ge][3] * rl) };
    *(uint2*)&orow[ge * 16 + quad * 4] = pk;
  }
}

extern "C" void kernel_launch(void* const* d_in, const int* in_sizes, int n_in,
                              void* d_out, int out_size, void* d_ws, size_t ws_size,
                              hipStream_t stream){
  const float* x   = (const float*)d_in[0];
  const float* nsc = (const float*)d_in[1];
  const float* wq  = (const float*)d_in[2];
  const float* wk  = (const float*)d_in[3];
  const float* wv  = (const float*)d_in[4];
  const float* wo  = (const float*)d_in[5];
  const float* bo  = (const float*)d_in[6];
  char* ws = (char*)d_ws;
  const size_t MB = (size_t)1 << 20;

  u16* qb  = (u16*)(ws);
  u16* kb  = (u16*)(ws + 8  * MB);
  u16* vtb = (u16*)(ws + 16 * MB);
  u16* h   = (u16*)d_out;
  u16* wT  = (u16*)((char*)d_out + 8 * MB);
  u16* wqT = wT;
  u16* wkT = wT + (1u << 20);
  u16* wvT = wT + (2u << 20);
  u16* woT = kb;

  k_rmsnorm<<<NROW, 256, 0, stream>>>(x, nsc, h);
  k_wtrans<<<dim3(16, 16, 3), 256, 0, stream>>>(wq, wk, wv, wT);
  k_gemm<<<dim3(768), 256, 0, stream>>>(h, wqT, wkT, wvT, qb, kb, vtb, nullptr, 1);
  k_attn<<<dim3(512), 512, 0, stream>>>(qb, kb, vtb, qb);
  k_wtrans<<<dim3(16, 16, 1), 256, 0, stream>>>(wo, wo, wo, woT);
  k_gemm<<<dim3(256), 256, 0, stream>>>(qb, woT, woT, woT, d_out, d_out, d_out, bo, 0);
}

// Round 4
// 206.828 us; speedup vs baseline: 1.1754x; 1.0185x over previous
//
#include <hip/hip_runtime.h>

typedef unsigned short u16;
typedef unsigned int   u32;
typedef __attribute__((ext_vector_type(8))) short bf16x8;
typedef __attribute__((ext_vector_type(4))) float f32x4;

#define SEQ 2048
#define DIM 1024
#define NH  16
#define DH  64
#define NROW 4096

static __device__ __forceinline__ u16 f2bf(float f){
  u32 u; __builtin_memcpy(&u, &f, 4);
  u32 r = (u + 0x7fffu + ((u >> 16) & 1u)) >> 16;
  return (u16)r;
}
// round-half-up pack of two fp32 -> two bf16 in one u32 (low = a, high = b)
static __device__ __forceinline__ u32 pack2bf(float a, float b){
  u32 ua, ub; __builtin_memcpy(&ua, &a, 4); __builtin_memcpy(&ub, &b, 4);
  return ((ua + 0x8000u) >> 16) | ((ub + 0x8000u) & 0xFFFF0000u);
}
// single-instruction RNE pack (lo = a, hi = b)
static __device__ __forceinline__ u32 cvt_pk_bf16(float a, float b){
  u32 r;
  asm("v_cvt_pk_bf16_f32 %0, %1, %2" : "=v"(r) : "v"(a), "v"(b));
  return r;
}

#define GLD_LDS(gp, lp) \
  __builtin_amdgcn_global_load_lds( \
      (const __attribute__((address_space(1))) void*)(gp), \
      (__attribute__((address_space(3))) void*)(lp), 16, 0, 0)

// counted waitcnt with compiler memory fence (blocks ds_read/GLD motion across)
#define WAIT_VM(N) asm volatile("s_waitcnt vmcnt(" #N ")" ::: "memory")
#define CFENCE()   asm volatile("" ::: "memory")

// ---------------- RMSNorm: x[4096][1024] fp32 -> h bf16 ----------------
__global__ __launch_bounds__(256) void k_rmsnorm(const float* __restrict__ x,
                                                 const float* __restrict__ sc,
                                                 u16* __restrict__ h){
  int row = blockIdx.x, t = threadIdx.x;
  float4 v = ((const float4*)(x + (size_t)row * DIM))[t];
  float ss = v.x*v.x + v.y*v.y + v.z*v.z + v.w*v.w;
  #pragma unroll
  for (int d = 32; d; d >>= 1) ss += __shfl_down(ss, d, 64);
  __shared__ float red[4];
  if ((t & 63) == 0) red[t >> 6] = ss;
  __syncthreads();
  float tot = red[0] + red[1] + red[2] + red[3];
  float rms = rsqrtf(tot * (1.0f / DIM) + 1e-6f);
  float4 s4 = ((const float4*)sc)[t];
  u16 ov[4];
  ov[0] = f2bf(v.x * rms * s4.x);
  ov[1] = f2bf(v.y * rms * s4.y);
  ov[2] = f2bf(v.z * rms * s4.z);
  ov[3] = f2bf(v.w * rms * s4.w);
  ((uint2*)(h + (size_t)row * DIM))[t] = *(uint2*)ov;
}

// ------- Weight transpose: fp32 K-major [1024][1024] -> bf16 N-major [n][k] -------
__global__ __launch_bounds__(256) void k_wtrans(const float* __restrict__ in0,
                                                const float* __restrict__ in1,
                                                const float* __restrict__ in2,
                                                u16* __restrict__ outT){
  __shared__ u16 tile[64][68];
  int t = threadIdx.x;
  int c0 = blockIdx.x * 64;   // n
  int r0 = blockIdx.y * 64;   // k
  int z = blockIdx.z;
  const float* in = (z == 0) ? in0 : ((z == 1) ? in1 : in2);
  u16* out = outT + (size_t)z * (1u << 20);
  #pragma unroll
  for (int i = 0; i < 4; i++){
    int idx = t + 256 * i;
    int r = idx >> 4, c4 = (idx & 15) * 4;
    float4 v = *(const float4*)&in[(size_t)(r0 + r) * 1024 + c0 + c4];
    u16 pk[4] = {f2bf(v.x), f2bf(v.y), f2bf(v.z), f2bf(v.w)};
    *(uint2*)&tile[r][c4] = *(uint2*)pk;
  }
  __syncthreads();
  #pragma unroll
  for (int i = 0; i < 2; i++){
    int c = t + 256 * i;
    int n = c >> 3, koff = (c & 7) * 8;
    alignas(16) u16 vals[8];
    #pragma unroll
    for (int j = 0; j < 8; j++) vals[j] = tile[koff + j][n];
    *(uint4*)&out[(size_t)(c0 + n) * 1024 + r0 + koff] = *(uint4*)vals;
  }
}

// ---------------- GEMM: C = A(bf16) x Bt^T, triple-buffered counted-vmcnt ---------
__global__ __launch_bounds__(256) void k_gemm(const u16* __restrict__ A,
                                              const u16* __restrict__ B0,
                                              const u16* __restrict__ B1,
                                              const u16* __restrict__ B2,
                                              void* __restrict__ C0,
                                              void* __restrict__ C1,
                                              void* __restrict__ C2,
                                              const float* __restrict__ bias,
                                              int qkv){
  __shared__ u16 Al[3][128][32];
  __shared__ u16 Bl[3][128][32];
  int t = threadIdx.x, lane = t & 63, w = t >> 6;
  int wm = w & 1, wn = w >> 1;
  int mrow = lane & 15, quad = lane >> 4;

  int nwgs = qkv ? 768 : 256;
  int cpx = nwgs >> 3;
  int id = blockIdx.x;
  int wg = (id & 7) * cpx + (id >> 3);
  int z = wg >> 8;
  int rem = wg & 255;
  int m0 = (rem >> 3) << 7;   // m-minor within XCD chunk
  int n0 = (rem & 7) << 7;
  const u16* Bt = (z == 0) ? B0 : ((z == 1) ? B1 : B2);

  int r0s = (t * 16) >> 6, off0 = ((t * 16) & 63) >> 1;   // i=0
  int r1s = r0s + 64;                                     // i=1

  const u16* Ap0 = &A [(size_t)(m0 + r0s) * 1024 + off0];
  const u16* Ap1 = &A [(size_t)(m0 + r1s) * 1024 + off0];
  const u16* Bp0 = &Bt[(size_t)(n0 + r0s) * 1024 + off0];
  const u16* Bp1 = &Bt[(size_t)(n0 + r1s) * 1024 + off0];

  f32x4 acc[4][4];
  #pragma unroll
  for (int ms = 0; ms < 4; ms++)
    #pragma unroll
    for (int ns = 0; ns < 4; ns++) acc[ms][ns] = (f32x4){0.f, 0.f, 0.f, 0.f};

  // prologue: stage tiles 0 and 1
  GLD_LDS(Ap0,      &Al[0][r0s][off0]);
  GLD_LDS(Ap1,      &Al[0][r1s][off0]);
  GLD_LDS(Bp0,      &Bl[0][r0s][off0]);
  GLD_LDS(Bp1,      &Bl[0][r1s][off0]);
  GLD_LDS(Ap0 + 32, &Al[1][r0s][off0]);
  GLD_LDS(Ap1 + 32, &Al[1][r1s][off0]);
  GLD_LDS(Bp0 + 32, &Bl[1][r0s][off0]);
  GLD_LDS(Bp1 + 32, &Bl[1][r1s][off0]);

  int cur = 0, pf = 2;
  for (int kt = 0; kt < 32; kt++){
    if (kt < 31) WAIT_VM(4); else WAIT_VM(0);
    __builtin_amdgcn_s_barrier();
    CFENCE();
    if (kt < 30){
      int K2 = (kt + 2) * 32;
      GLD_LDS(Ap0 + K2, &Al[pf][r0s][off0]);
      GLD_LDS(Ap1 + K2, &Al[pf][r1s][off0]);
      GLD_LDS(Bp0 + K2, &Bl[pf][r0s][off0]);
      GLD_LDS(Bp1 + K2, &Bl[pf][r1s][off0]);
    }
    bf16x8 af[4], bfr[4];
    #pragma unroll
    for (int ms = 0; ms < 4; ms++)
      af[ms] = *(const bf16x8*)&Al[cur][wm * 64 + ms * 16 + mrow][quad * 8];
    #pragma unroll
    for (int ns = 0; ns < 4; ns++)
      bfr[ns] = *(const bf16x8*)&Bl[cur][wn * 64 + ns * 16 + mrow][quad * 8];
    #pragma unroll
    for (int ms = 0; ms < 4; ms++)
      #pragma unroll
      for (int ns = 0; ns < 4; ns++)
        acc[ms][ns] = __builtin_amdgcn_mfma_f32_16x16x32_bf16(af[ms], bfr[ns], acc[ms][ns], 0, 0, 0);
    cur = (cur == 2) ? 0 : cur + 1;
    pf  = (pf  == 2) ? 0 : pf  + 1;
  }

  float qscale = (qkv && z == 0) ? 0.180336880111112f : 1.0f;
  bool  vmode  = (qkv && z == 2);
  void* C = (z == 0) ? C0 : ((z == 1) ? C1 : C2);

  #pragma unroll
  for (int ms = 0; ms < 4; ms++){
    #pragma unroll
    for (int ns = 0; ns < 4; ns++){
      int col = n0 + wn * 64 + ns * 16 + mrow;
      int rbase = m0 + wm * 64 + ms * 16 + quad * 4;
      if (vmode){
        int b = rbase >> 11, sl = rbase & 2047;
        int hh = col >> 6, e = col & 63;
        uint2 pk = { pack2bf(acc[ms][ns][0], acc[ms][ns][1]),
                     pack2bf(acc[ms][ns][2], acc[ms][ns][3]) };
        *(uint2*)&((u16*)C)[(size_t)((b * NH + hh) * DH + e) * SEQ + sl] = pk;
      } else if (qkv){
        #pragma unroll
        for (int r = 0; r < 4; r++)
          ((u16*)C)[(size_t)(rbase + r) * 1024 + col] = f2bf(acc[ms][ns][r] * qscale);
      } else {
        float bv = bias ? bias[col] : 0.f;
        #pragma unroll
        for (int r = 0; r < 4; r++)
          ((float*)C)[(size_t)(rbase + r) * 1024 + col] = acc[ms][ns][r] + bv;
      }
    }
  }
}

// ---------------- Flash attention: 4 waves x 32 q-rows, 64-row K/V tile -----------
// LDS-amplification fix: each wave now serves TWO q-groups (qg0: rows w*32+mrow,
// qg1: +16) from one K/V fragment read -> per-q LDS traffic halved vs 8x16.
// Triple-buffered staging, counted vmcnt(4), raw s_barrier, issue-after-barrier.
// XOR-swizzled linear LDS (pre-swizzled global source, f(row)=(row&3)|(((row>>3)&1)<<2);
// f invariant under row+32 so one lc serves both staged halves). QK^T A-rows
// permuted so lane's C output IS the PV B-fragment. Denominator via ones x P MFMA.
// Bare v_exp_f32 via __builtin_amdgcn_exp2f (no OCML denorm fixup).
__global__ __launch_bounds__(256) void k_attn(const u16* q,
                                              const u16* __restrict__ k,
                                              const u16* __restrict__ vt,
                                              u16* nv){
  __shared__ u16 Kl[3][64][64];
  __shared__ u16 Vl[3][64][64];
  int t = threadIdx.x, lane = t & 63, w = t >> 6;    // w in 0..3
  int mrow = lane & 15, quad = lane >> 4;
  int id = blockIdx.x;
  int wg = (id & 7) * 64 + (id >> 3);                // 512 wgs, 64/XCD chunk
  int s0 = (wg & 15) * 128;
  int bh = wg >> 4; int b = bh >> 4, hh = bh & 15;

  const u16* qrow0 = q + (size_t)((b * SEQ + s0 + w * 32 + mrow) * NH + hh) * DH;
  const u16* qrow1 = qrow0 + 16 * NH * DH;
  bf16x8 bq[2][2];
  bq[0][0] = *(const bf16x8*)(qrow0 + quad * 8);
  bq[0][1] = *(const bf16x8*)(qrow0 + 32 + quad * 8);
  bq[1][0] = *(const bf16x8*)(qrow1 + quad * 8);
  bq[1][1] = *(const bf16x8*)(qrow1 + 32 + quad * 8);

  // staging coords: thread t (0..255) writes LDS bytes t*16 (rows 0..31) and
  // t*16+4096 (rows 32..63); f(row) identical for both halves.
  int rw  = t >> 3;                                  // 0..31
  int fst = (rw & 3) | (((t >> 6) & 1) << 2);
  int lc  = (t & 7) ^ fst;                           // logical chunk to fetch
  const u16* kp = k  + ((size_t)b * SEQ + rw) * (NH * DH) + hh * DH + lc * 8;
  const u16* vp = vt + ((size_t)bh * DH + rw) * SEQ + lc * 8;

  // read coords
  int row0 = ((mrow >> 2) << 3) | (mrow & 3);                       // pi_0(mrow)
  int cK = (quad ^ ((mrow & 3) | (((mrow >> 2) & 1) << 2))) << 4;   // byte of a0 chunk
  int cV = (quad ^ ((mrow & 3) | (((mrow >> 3) & 1) << 2))) << 4;

  f32x4 o[2][4];
  #pragma unroll
  for (int qg = 0; qg < 2; qg++)
    #pragma unroll
    for (int g = 0; g < 4; g++) o[qg][g] = (f32x4){0.f, 0.f, 0.f, 0.f};
  f32x4 accl[2];
  accl[0] = (f32x4){0.f, 0.f, 0.f, 0.f};
  accl[1] = (f32x4){0.f, 0.f, 0.f, 0.f};
  bf16x8 onesf;
  #pragma unroll
  for (int j = 0; j < 8; j++) onesf[j] = (short)0x3F80;             // bf16 1.0

  // prologue: stage tiles 0 and 1 (4 GLDs per tile: K lo/hi, V lo/hi)
  #pragma unroll
  for (int pt = 0; pt < 2; pt++){
    u16* dK = (u16*)Kl[pt]; u16* dV = (u16*)Vl[pt];
    GLD_LDS(kp,                dK + (t << 3));
    GLD_LDS(kp + 32 * NH * DH, dK + 2048 + (t << 3));
    GLD_LDS(vp,                dV + (t << 3));
    GLD_LDS(vp + 32 * SEQ,     dV + 2048 + (t << 3));
    kp += 64 * NH * DH; vp += 64;
  }

  int cur = 0, pf = 2;
  for (int kt = 0; kt < 32; kt++){
    if (kt < 31) WAIT_VM(4); else WAIT_VM(0);
    __builtin_amdgcn_s_barrier();
    CFENCE();
    if (kt < 30){                                    // issue tile kt+2 (async)
      u16* dK = (u16*)Kl[pf]; u16* dV = (u16*)Vl[pf];
      GLD_LDS(kp,                dK + (t << 3));
      GLD_LDS(kp + 32 * NH * DH, dK + 2048 + (t << 3));
      GLD_LDS(vp,                dV + (t << 3));
      GLD_LDS(vp + 32 * SEQ,     dV + 2048 + (t << 3));
      kp += 64 * NH * DH; vp += 64;
    }

    // QK^T, K fragment shared by both q-groups: lane holds S^T[kk=quad*8+j][q]
    const char* Kb = (const char*)Kl[cur];
    f32x4 sT[2][4];
    __builtin_amdgcn_s_setprio(1);
    #pragma unroll
    for (int g = 0; g < 4; g++){
      int rg = row0 + ((g & 1) << 2) + ((g >> 1) << 5);   // +0,+4,+32,+36
      const char* rp = Kb + rg * 128;
      bf16x8 a0 = *(const bf16x8*)(rp + cK);
      bf16x8 a1 = *(const bf16x8*)(rp + (cK ^ 64));
      f32x4 z0 = (f32x4){0.f, 0.f, 0.f, 0.f};
      f32x4 z1 = (f32x4){0.f, 0.f, 0.f, 0.f};
      z0 = __builtin_amdgcn_mfma_f32_16x16x32_bf16(a0, bq[0][0], z0, 0, 0, 0);
      z1 = __builtin_amdgcn_mfma_f32_16x16x32_bf16(a0, bq[1][0], z1, 0, 0, 0);
      z0 = __builtin_amdgcn_mfma_f32_16x16x32_bf16(a1, bq[0][1], z0, 0, 0, 0);
      z1 = __builtin_amdgcn_mfma_f32_16x16x32_bf16(a1, bq[1][1], z1, 0, 0, 0);
      sT[0][g] = z0; sT[1][g] = z1;
    }
    __builtin_amdgcn_s_setprio(0);

    // exp2 + pack in-register (bare v_exp_f32)
    bf16x8 pb[2][2];
    #pragma unroll
    for (int qg = 0; qg < 2; qg++){
      u32 wd[8];
      #pragma unroll
      for (int g = 0; g < 4; g++){
        float e0 = __builtin_amdgcn_exp2f(sT[qg][g][0]);
        float e1 = __builtin_amdgcn_exp2f(sT[qg][g][1]);
        float e2 = __builtin_amdgcn_exp2f(sT[qg][g][2]);
        float e3 = __builtin_amdgcn_exp2f(sT[qg][g][3]);
        wd[g * 2]     = cvt_pk_bf16(e0, e1);
        wd[g * 2 + 1] = cvt_pk_bf16(e2, e3);
      }
      union { u32 u[4]; bf16x8 v; } U0, U1;
      U0.u[0] = wd[0]; U0.u[1] = wd[1]; U0.u[2] = wd[2]; U0.u[3] = wd[3];
      U1.u[0] = wd[4]; U1.u[1] = wd[5]; U1.u[2] = wd[6]; U1.u[3] = wd[7];
      pb[qg][0] = U0.v; pb[qg][1] = U1.v;
    }

    __builtin_amdgcn_s_setprio(1);
    // denominator on the matrix pipe
    #pragma unroll
    for (int qg = 0; qg < 2; qg++){
      accl[qg] = __builtin_amdgcn_mfma_f32_16x16x32_bf16(onesf, pb[qg][0], accl[qg], 0, 0, 0);
      accl[qg] = __builtin_amdgcn_mfma_f32_16x16x32_bf16(onesf, pb[qg][1], accl[qg], 0, 0, 0);
    }

    // O^T[e][q] += V^T[e][kk] . P[kk][q] ; V fragment shared by both q-groups
    const char* Vb = (const char*)Vl[cur];
    #pragma unroll
    for (int ge = 0; ge < 4; ge++){
      const char* rp = Vb + (ge * 16 + mrow) * 128;
      bf16x8 v0 = *(const bf16x8*)(rp + cV);
      bf16x8 v1 = *(const bf16x8*)(rp + (cV ^ 64));
      o[0][ge] = __builtin_amdgcn_mfma_f32_16x16x32_bf16(v0, pb[0][0], o[0][ge], 0, 0, 0);
      o[1][ge] = __builtin_amdgcn_mfma_f32_16x16x32_bf16(v0, pb[1][0], o[1][ge], 0, 0, 0);
      o[0][ge] = __builtin_amdgcn_mfma_f32_16x16x32_bf16(v1, pb[0][1], o[0][ge], 0, 0, 0);
      o[1][ge] = __builtin_amdgcn_mfma_f32_16x16x32_bf16(v1, pb[1][1], o[1][ge], 0, 0, 0);
    }
    __builtin_amdgcn_s_setprio(0);

    cur = (cur == 2) ? 0 : cur + 1;
    pf  = (pf  == 2) ? 0 : pf  + 1;
  }

  // epilogue: lane's q = mrow (+16 for qg1); e = ge*16 + quad*4 + r
  float rl0 = 1.0f / accl[0][0];
  float rl1 = 1.0f / accl[1][0];
  u16* orow0 = nv + (size_t)((b * SEQ + s0 + w * 32 + mrow) * NH + hh) * DH;
  u16* orow1 = orow0 + 16 * NH * DH;
  #pragma unroll
  for (int ge = 0; ge < 4; ge++){
    uint2 pk0 = { cvt_pk_bf16(o[0][ge][0] * rl0, o[0][ge][1] * rl0),
                  cvt_pk_bf16(o[0][ge][2] * rl0, o[0][ge][3] * rl0) };
    *(uint2*)&orow0[ge * 16 + quad * 4] = pk0;
    uint2 pk1 = { cvt_pk_bf16(o[1][ge][0] * rl1, o[1][ge][1] * rl1),
                  cvt_pk_bf16(o[1][ge][2] * rl1, o[1][ge][3] * rl1) };
    *(uint2*)&orow1[ge * 16 + quad * 4] = pk1;
  }
}

extern "C" void kernel_launch(void* const* d_in, const int* in_sizes, int n_in,
                              void* d_out, int out_size, void* d_ws, size_t ws_size,
                              hipStream_t stream){
  const float* x   = (const float*)d_in[0];
  const float* nsc = (const float*)d_in[1];
  const float* wq  = (const float*)d_in[2];
  const float* wk  = (const float*)d_in[3];
  const float* wv  = (const float*)d_in[4];
  const float* wo  = (const float*)d_in[5];
  const float* bo  = (const float*)d_in[6];
  char* ws = (char*)d_ws;
  const size_t MB = (size_t)1 << 20;

  u16* qb  = (u16*)(ws);
  u16* kb  = (u16*)(ws + 8  * MB);
  u16* vtb = (u16*)(ws + 16 * MB);
  u16* h   = (u16*)d_out;
  u16* wT  = (u16*)((char*)d_out + 8 * MB);
  u16* wqT = wT;
  u16* wkT = wT + (1u << 20);
  u16* wvT = wT + (2u << 20);
  u16* woT = kb;

  k_rmsnorm<<<NROW, 256, 0, stream>>>(x, nsc, h);
  k_wtrans<<<dim3(16, 16, 3), 256, 0, stream>>>(wq, wk, wv, wT);
  k_gemm<<<dim3(768), 256, 0, stream>>>(h, wqT, wkT, wvT, qb, kb, vtb, nullptr, 1);
  k_attn<<<dim3(512), 256, 0, stream>>>(qb, kb, vtb, qb);
  k_wtrans<<<dim3(16, 16, 1), 256, 0, stream>>>(wo, wo, wo, woT);
  k_gemm<<<dim3(256), 256, 0, stream>>>(qb, woT, woT, woT, d_out, d_out, d_out, bo, 0);
}